// Round 6
// baseline (40927.631 us; speedup 1.0000x reference)
//
#include <hip/hip_runtime.h>
#include <stdint.h>

// DSNN bit-exact fp32. Locked-in facts:
//  - Ref is k-ascending single-accumulator fma (R1/R4/R5 absmax 0.0); any
//    reordering/reprecision flips spikes chaotically (R2: 511). Dense fmaf
//    with spike in {0.0,1.0} is bitwise == conditional add. No MFMA.
//  - R4 vs R5: same VALUBusy 53% at 1 WG/CU and 2 WG/CU -> NOT barrier-bound.
//    Cause: W bytes per fma. 4rows x 4cols = 1 KB W per 16-fma wave-j ->
//    114 B/cyc/CU demand vs ~64 B/cyc L1 -> caps at ~56%. Fix: 16 rows x
//    2 cols per thread -> 512 B W per 32-fma wave-j -> ~26 B/cyc. L1 unbound.
//  - State (m0,s1,m1,s2,m2 = 160 regs) + acc(32) in VGPRs, 2 waves/SIMD.
//    h0 parked in LDS (private re-read, cheap). Spike broadcasts from LDS
//    at wave-uniform addresses (free).

typedef __attribute__((ext_vector_type(2))) float f32x2;
typedef __attribute__((ext_vector_type(4))) float f32x4;

#define ALPHA 0.9f
#define BETA 0.85f
#define NSTEPS 127
#define WGT 512
#define ROWS 32
#define CPAD 36     // spkbuf col stride (floats): 32 rows + 4 pad
#define HPAD 516    // h0buf row stride (floats)

// Update forms verbatim from R1/R4/R5 (bit-exact-verified vs np reference).
#define LIF_L0(M, H, SP) { float _m = BETA * (M) + (H); \
    const bool _b = (_m - 1.0f) > 0.0f; (M) = _b ? 0.0f : _m; \
    (SP) = _b ? 1.0f : 0.0f; }
#define LIF_MID(S, M, A, SP) { (S) = ALPHA * (S) + (A); \
    float _m = BETA * (M) + (S); const bool _b = (_m - 1.0f) > 0.0f; \
    (M) = _b ? 0.0f : _m; (SP) = _b ? 1.0f : 0.0f; }
#define LIF_OUT(S, M, A) { (S) = ALPHA * (S) + (A); (M) = BETA * (M) + (S); }

__global__ __launch_bounds__(WGT, 2)
void dsnn_kernel(const float* __restrict__ x,
                 const float* __restrict__ W0,
                 const float* __restrict__ W1,
                 const float* __restrict__ W2,
                 float* __restrict__ out)
{
    __shared__ float spkbuf[512 * CPAD];   // 73728 B, [col][row] (x-stage, then spikes)
    __shared__ float h0buf[ROWS * HPAD];   // 66048 B, [row][col]

    const int t  = threadIdx.x;
    const int c2 = (t & 255) * 2;          // cols c2, c2+1
    const int g  = (t >> 8) * 16;          // rows g..g+15 (wave-uniform)
    const int r0 = blockIdx.x * ROWS;

    // ---- stage x (pos/neg split) into spkbuf [i][row], i = 0..255 ----
    for (int k = t; k < 256 * ROWS; k += WGT) {
        const int i = k >> 5;
        const int r = k & 31;
        const float v = (i < 128) ? x[(size_t)(r0 + r) * 128 + i]
                                  : -x[(size_t)(r0 + r) * 128 + (i - 128)];
        spkbuf[i * CPAD + r] = fmaxf(v, 0.0f);
    }
    __syncthreads();

    float acc[16][2];   // [row r][col cc]

    // acc[r][cc] += buf[j][g+r] * W[j][c2+cc], j ascending (bit-exact order)
    auto gemm = [&](const float* Wcol, int K) {
        #pragma unroll 4
        for (int j = 0; j < K; ++j) {
            const float* sb = spkbuf + j * CPAD + g;     // wave-uniform -> broadcast
            const f32x4 sA = *(const f32x4*)(sb);
            const f32x4 sB = *(const f32x4*)(sb + 4);
            const f32x4 sC = *(const f32x4*)(sb + 8);
            const f32x4 sD = *(const f32x4*)(sb + 12);
            const f32x2 wv = *(const f32x2*)(Wcol + (size_t)j * 512);
            #pragma unroll
            for (int rr = 0; rr < 4; ++rr) {
                acc[rr][0]      = fmaf(sA[rr], wv.x, acc[rr][0]);
                acc[rr][1]      = fmaf(sA[rr], wv.y, acc[rr][1]);
                acc[4 + rr][0]  = fmaf(sB[rr], wv.x, acc[4 + rr][0]);
                acc[4 + rr][1]  = fmaf(sB[rr], wv.y, acc[4 + rr][1]);
                acc[8 + rr][0]  = fmaf(sC[rr], wv.x, acc[8 + rr][0]);
                acc[8 + rr][1]  = fmaf(sC[rr], wv.y, acc[8 + rr][1]);
                acc[12 + rr][0] = fmaf(sD[rr], wv.x, acc[12 + rr][0]);
                acc[12 + rr][1] = fmaf(sD[rr], wv.y, acc[12 + rr][1]);
            }
        }
    };

    // ---- h0 = x @ W0 (time-invariant), park in LDS ----
    #pragma unroll
    for (int r = 0; r < 16; ++r) { acc[r][0] = 0.0f; acc[r][1] = 0.0f; }
    gemm(W0 + c2, 256);
    #pragma unroll
    for (int r = 0; r < 16; ++r) {
        f32x2 hv = { acc[r][0], acc[r][1] };
        *(f32x2*)(h0buf + (g + r) * HPAD + c2) = hv;
    }
    __syncthreads();   // all x-reads done before spkbuf is reused for spikes

    // ---- recurrent state in registers ----
    float m0[16][2], s1[16][2], m1[16][2], s2[16][2], m2[16][2];
    #pragma unroll
    for (int r = 0; r < 16; ++r)
        #pragma unroll
        for (int cc = 0; cc < 2; ++cc) {
            m0[r][cc] = 0.f; s1[r][cc] = 0.f; m1[r][cc] = 0.f;
            s2[r][cc] = 0.f; m2[r][cc] = 0.f;
        }

    for (int step = 0; step < NSTEPS; ++step) {
        // ===== layer 0: m0 = BETA*m0 + h0; spike; reset; spikes -> spkbuf =====
        #pragma unroll
        for (int rg = 0; rg < 4; ++rg) {
            f32x4 sv0, sv1;
            #pragma unroll
            for (int rr = 0; rr < 4; ++rr) {
                const int r = rg * 4 + rr;
                const f32x2 hv = *(const f32x2*)(h0buf + (g + r) * HPAD + c2);
                LIF_L0(m0[r][0], hv.x, sv0[rr]);
                LIF_L0(m0[r][1], hv.y, sv1[rr]);
            }
            *(f32x4*)(spkbuf + c2 * CPAD + g + rg * 4)       = sv0;
            *(f32x4*)(spkbuf + (c2 + 1) * CPAD + g + rg * 4) = sv1;
        }
        __syncthreads();                       // A: L0 spikes visible

        // ===== layer 1: h1 = spk0 @ W1 =====
        #pragma unroll
        for (int r = 0; r < 16; ++r) { acc[r][0] = 0.0f; acc[r][1] = 0.0f; }
        gemm(W1 + c2, 512);
        __syncthreads();                       // B: all reads of L0 spikes done

        #pragma unroll
        for (int rg = 0; rg < 4; ++rg) {
            f32x4 sv0, sv1;
            #pragma unroll
            for (int rr = 0; rr < 4; ++rr) {
                const int r = rg * 4 + rr;
                LIF_MID(s1[r][0], m1[r][0], acc[r][0], sv0[rr]);
                LIF_MID(s1[r][1], m1[r][1], acc[r][1], sv1[rr]);
            }
            *(f32x4*)(spkbuf + c2 * CPAD + g + rg * 4)       = sv0;
            *(f32x4*)(spkbuf + (c2 + 1) * CPAD + g + rg * 4) = sv1;
        }
        __syncthreads();                       // C: L1 spikes visible

        // ===== layer 2: h2 = spk1 @ W2; s2,m2 update; no reset =====
        #pragma unroll
        for (int r = 0; r < 16; ++r) { acc[r][0] = 0.0f; acc[r][1] = 0.0f; }
        gemm(W2 + c2, 512);
        #pragma unroll
        for (int r = 0; r < 16; ++r) {
            LIF_OUT(s2[r][0], m2[r][0], acc[r][0]);
            LIF_OUT(s2[r][1], m2[r][1], acc[r][1]);
        }
        __syncthreads();                       // D: L1-spike reads done before next L0 write
    }

    // ---- write final m2 ----
    #pragma unroll
    for (int r = 0; r < 16; ++r) {
        f32x2 ov = { m2[r][0], m2[r][1] };
        *(f32x2*)(out + (size_t)(r0 + g + r) * 512 + c2) = ov;
    }
}

extern "C" void kernel_launch(void* const* d_in, const int* in_sizes, int n_in,
                              void* d_out, int out_size, void* d_ws, size_t ws_size,
                              hipStream_t stream) {
    const float* inputs = (const float*)d_in[0];   // 16384 x 128
    const float* W0     = (const float*)d_in[1];   // 256 x 512
    const float* W1     = (const float*)d_in[2];   // 512 x 512
    const float* W2     = (const float*)d_in[3];   // 512 x 512
    float* out          = (float*)d_out;           // 16384 x 512

    dim3 grid(16384 / ROWS);     // 512 workgroups, 32 rows each
    dim3 block(WGT);
    dsnn_kernel<<<grid, block, 0, stream>>>(inputs, W0, W1, W2, out);
}

// Round 7
// 32994.461 us; speedup vs baseline: 1.2404x; 1.2404x over previous
//
#include <hip/hip_runtime.h>
#include <stdint.h>

// DSNN bit-exact fp32. Locked-in facts:
//  - Ref is k-ascending single-accumulator fma (R1/R4/R5/R6 absmax 0.0); any
//    reorder/reprecision flips spikes chaotically (R2: 511). Dense fmaf with
//    spike in {0.0,1.0} is bitwise == conditional add. No MFMA.
//  - Pipe model (fits R4/R5/R6): per CU-j VALU=128cyc fixed; TCP~64B/cyc.
//    R4 (4x4): W dwordx4 -> 256 TCP cyc -> 2:1 bound -> 53%. R6 (16x2):
//    TCP ok but 8 waves/CU + reg overflow (pool=512/SIMD -> 128/wave at
//    4 waves/SIMD) -> latency-starved 41%.
//  - R7: cells=16 as 8 rows x 2 cols => regs ~120 fits 128 @ 16 waves/CU;
//    W dwordx2 = 8 TCP lines/wave-j -> TCP 128 = VALU 128 = LDS ~128 (1:1:1
//    on independent pipes, 16 waves overlap them). h0 stays in LDS (regs,
//    not LDS, bind occupancy -> 140 KB is free).

typedef __attribute__((ext_vector_type(2))) float f32x2;
typedef __attribute__((ext_vector_type(4))) float f32x4;

#define ALPHA 0.9f
#define BETA 0.85f
#define NSTEPS 127
#define WGT 1024
#define ROWS 32
#define CPAD 36     // spkbuf col stride (floats): 32 rows + 4 pad; j-stride 144 B (16B mult)
#define HPAD 516    // h0buf row stride (floats)

// Update forms verbatim from R1/R4 (bit-exact-verified vs np reference).
#define LIF_L0(M, H, SP) { float _m = BETA * (M) + (H); \
    const bool _b = (_m - 1.0f) > 0.0f; (M) = _b ? 0.0f : _m; \
    (SP) = _b ? 1.0f : 0.0f; }
#define LIF_MID(S, M, A, SP) { (S) = ALPHA * (S) + (A); \
    float _m = BETA * (M) + (S); const bool _b = (_m - 1.0f) > 0.0f; \
    (M) = _b ? 0.0f : _m; (SP) = _b ? 1.0f : 0.0f; }
#define LIF_OUT(S, M, A) { (S) = ALPHA * (S) + (A); (M) = BETA * (M) + (S); }

__global__ __launch_bounds__(WGT, 4)
void dsnn_kernel(const float* __restrict__ x,
                 const float* __restrict__ W0,
                 const float* __restrict__ W1,
                 const float* __restrict__ W2,
                 float* __restrict__ out)
{
    __shared__ float spkbuf[512 * CPAD];   // 73728 B, [index][row] (x-stage, then spikes)
    __shared__ float h0buf[ROWS * HPAD];   // 66048 B, [row][col]

    const int t  = threadIdx.x;
    const int c2 = (t & 255) * 2;          // cols c2, c2+1
    const int g  = (t >> 8) * 8;           // rows g..g+7 (wave-uniform)
    const int r0 = blockIdx.x * ROWS;

    // ---- stage x (pos/neg split) into spkbuf [i][row], i = 0..255 ----
    for (int k = t; k < 256 * ROWS; k += WGT) {
        const int i = k >> 5;
        const int r = k & 31;
        const float v = (i < 128) ? x[(size_t)(r0 + r) * 128 + i]
                                  : -x[(size_t)(r0 + r) * 128 + (i - 128)];
        spkbuf[i * CPAD + r] = fmaxf(v, 0.0f);
    }
    __syncthreads();

    float acc[8][2];   // [row r][col cc]

    // acc[r][cc] += buf[j][g+r] * W[j][c2+cc], j ascending (bit-exact order)
    auto gemm = [&](const float* Wcol, int K) {
        #pragma unroll 2
        for (int j = 0; j < K; ++j) {
            const float* sb = spkbuf + j * CPAD + g;       // wave-uniform -> broadcast
            const f32x4 sA = *(const f32x4*)(sb);          // rows g..g+3
            const f32x4 sB = *(const f32x4*)(sb + 4);      // rows g+4..g+7
            const f32x2 wv = *(const f32x2*)(Wcol + (size_t)j * 512);
            #pragma unroll
            for (int rr = 0; rr < 4; ++rr) {
                acc[rr][0]     = fmaf(sA[rr], wv.x, acc[rr][0]);
                acc[rr][1]     = fmaf(sA[rr], wv.y, acc[rr][1]);
                acc[4 + rr][0] = fmaf(sB[rr], wv.x, acc[4 + rr][0]);
                acc[4 + rr][1] = fmaf(sB[rr], wv.y, acc[4 + rr][1]);
            }
        }
    };

    // ---- h0 = x @ W0 (time-invariant), park in LDS ----
    #pragma unroll
    for (int r = 0; r < 8; ++r) { acc[r][0] = 0.0f; acc[r][1] = 0.0f; }
    gemm(W0 + c2, 256);
    #pragma unroll
    for (int r = 0; r < 8; ++r) {
        f32x2 hv = { acc[r][0], acc[r][1] };
        *(f32x2*)(h0buf + (g + r) * HPAD + c2) = hv;
    }
    __syncthreads();   // all x-reads done before spkbuf is reused for spikes

    // ---- recurrent state in registers: 5 x 16 = 80 ----
    float m0[8][2], s1[8][2], m1[8][2], s2[8][2], m2[8][2];
    #pragma unroll
    for (int r = 0; r < 8; ++r)
        #pragma unroll
        for (int cc = 0; cc < 2; ++cc) {
            m0[r][cc] = 0.f; s1[r][cc] = 0.f; m1[r][cc] = 0.f;
            s2[r][cc] = 0.f; m2[r][cc] = 0.f;
        }

    for (int step = 0; step < NSTEPS; ++step) {
        // ===== layer 0: m0 = BETA*m0 + h0; spike; reset; spikes -> spkbuf =====
        {
            f32x4 svA[2], svB[2];   // [cc] rows g..g+3 / g+4..g+7
            #pragma unroll
            for (int rr = 0; rr < 4; ++rr) {
                const f32x2 hva = *(const f32x2*)(h0buf + (g + rr) * HPAD + c2);
                const f32x2 hvb = *(const f32x2*)(h0buf + (g + 4 + rr) * HPAD + c2);
                LIF_L0(m0[rr][0], hva.x, svA[0][rr]);
                LIF_L0(m0[rr][1], hva.y, svA[1][rr]);
                LIF_L0(m0[4 + rr][0], hvb.x, svB[0][rr]);
                LIF_L0(m0[4 + rr][1], hvb.y, svB[1][rr]);
            }
            #pragma unroll
            for (int cc = 0; cc < 2; ++cc) {
                *(f32x4*)(spkbuf + (c2 + cc) * CPAD + g)     = svA[cc];
                *(f32x4*)(spkbuf + (c2 + cc) * CPAD + g + 4) = svB[cc];
            }
        }
        __syncthreads();                       // A: L0 spikes visible

        // ===== layer 1: h1 = spk0 @ W1 =====
        #pragma unroll
        for (int r = 0; r < 8; ++r) { acc[r][0] = 0.0f; acc[r][1] = 0.0f; }
        gemm(W1 + c2, 512);
        __syncthreads();                       // B: all reads of L0 spikes done

        {
            f32x4 svA[2], svB[2];
            #pragma unroll
            for (int rr = 0; rr < 4; ++rr) {
                LIF_MID(s1[rr][0], m1[rr][0], acc[rr][0], svA[0][rr]);
                LIF_MID(s1[rr][1], m1[rr][1], acc[rr][1], svA[1][rr]);
                LIF_MID(s1[4 + rr][0], m1[4 + rr][0], acc[4 + rr][0], svB[0][rr]);
                LIF_MID(s1[4 + rr][1], m1[4 + rr][1], acc[4 + rr][1], svB[1][rr]);
            }
            #pragma unroll
            for (int cc = 0; cc < 2; ++cc) {
                *(f32x4*)(spkbuf + (c2 + cc) * CPAD + g)     = svA[cc];
                *(f32x4*)(spkbuf + (c2 + cc) * CPAD + g + 4) = svB[cc];
            }
        }
        __syncthreads();                       // C: L1 spikes visible

        // ===== layer 2: h2 = spk1 @ W2; s2,m2 update; no reset =====
        #pragma unroll
        for (int r = 0; r < 8; ++r) { acc[r][0] = 0.0f; acc[r][1] = 0.0f; }
        gemm(W2 + c2, 512);
        #pragma unroll
        for (int r = 0; r < 8; ++r) {
            LIF_OUT(s2[r][0], m2[r][0], acc[r][0]);
            LIF_OUT(s2[r][1], m2[r][1], acc[r][1]);
        }
        __syncthreads();                       // D: L1-spike reads done before next L0 write
    }

    // ---- write final m2 ----
    #pragma unroll
    for (int r = 0; r < 8; ++r) {
        f32x2 ov = { m2[r][0], m2[r][1] };
        *(f32x2*)(out + (size_t)(r0 + g + r) * 512 + c2) = ov;
    }
}

extern "C" void kernel_launch(void* const* d_in, const int* in_sizes, int n_in,
                              void* d_out, int out_size, void* d_ws, size_t ws_size,
                              hipStream_t stream) {
    const float* inputs = (const float*)d_in[0];   // 16384 x 128
    const float* W0     = (const float*)d_in[1];   // 256 x 512
    const float* W1     = (const float*)d_in[2];   // 512 x 512
    const float* W2     = (const float*)d_in[3];   // 512 x 512
    float* out          = (float*)d_out;           // 16384 x 512

    dim3 grid(16384 / ROWS);     // 512 workgroups, 32 rows each
    dim3 block(WGT);
    dsnn_kernel<<<grid, block, 0, stream>>>(inputs, W0, W1, W2, out);
}